// Round 1
// 159.381 us; speedup vs baseline: 1.1338x; 1.1338x over previous
//
#include <hip/hip_runtime.h>
#include <math.h>

typedef __bf16 bf16_t;
typedef __bf16 bf16x8 __attribute__((ext_vector_type(8)));
typedef __bf16 bf16x4 __attribute__((ext_vector_type(4)));
typedef float  floatx4 __attribute__((ext_vector_type(4)));

#define TT   4096
#define CD   1024
#define HSZ  64
#define NROW 16384
#define NEG_BIG (-1e30f)

// workspace element offsets (bf16)
#define WB_OFF 0                       // [kc][t12][512]  = 196608 elems
#define Q_OFF  196608                  // q[row][64]
#define K_OFF  (196608 + NROW * HSZ)   // K fragment tiles
#define V_OFF  (196608 + 2 * NROW * HSZ) // V fragment tiles

#if __has_builtin(__builtin_amdgcn_exp2f)
__device__ __forceinline__ float fexp2(float x) { return __builtin_amdgcn_exp2f(x); }
#else
__device__ __forceinline__ float fexp2(float x) { return exp2f(x); }
#endif

// cross-quad (lane ^16, ^32) reductions: a q-row's data lives on 4 lanes
__device__ __forceinline__ float qmax(float v) {
  v = fmaxf(v, __shfl_xor(v, 16));
  v = fmaxf(v, __shfl_xor(v, 32));
  return v;
}
__device__ __forceinline__ float qsum(float v) {
  v += __shfl_xor(v, 16);
  v += __shfl_xor(v, 32);
  return v;
}

// ---------------------------------------------------------------------------
// Kernel 0: fp32 weights -> bf16, layout [kc][t12][512] so a proj block's
// per-kc chunk (all 12 n-tiles' fragments) is one contiguous 12 KB.
// Fragment elem (lane,j) = W_wsel[n = nt*16+(lane&15)][k = kc*32+(lane>>4)*8+j].
// ---------------------------------------------------------------------------
__global__ __launch_bounds__(256, 1) void wcvt_kernel(
    const float* __restrict__ Wk, const float* __restrict__ Wq,
    const float* __restrict__ Wv, bf16_t* __restrict__ Wb)
{
  const int t    = blockIdx.x * 256 + threadIdx.x;  // 192 blocks
  const int e    = t * 4;
  const int tile = e >> 9;          // 0..383
  const int kc   = tile / 12;
  const int t12  = tile - kc * 12;
  const int r    = e & 511;
  const int lane = r >> 3;
  const int j0   = r & 7;
  const int wsel = t12 >> 2;
  const int nt   = t12 & 3;
  const int n    = nt * 16 + (lane & 15);
  const int k    = kc * 32 + (lane >> 4) * 8 + j0;
  const float* src = (wsel == 0) ? Wq : (wsel == 1) ? Wk : Wv;
  float4 f = *(const float4*)(src + n * CD + k);
  bf16x4 o;
  o[0] = (bf16_t)f.x; o[1] = (bf16_t)f.y; o[2] = (bf16_t)f.z; o[3] = (bf16_t)f.w;
  *(bf16x4*)(Wb + e) = o;
}

// ---------------------------------------------------------------------------
// Kernel 1: QKV projection with LDS-shared weights.  512 blocks x 4 waves;
// block owns 32 x-rows.  wave = rg*2+tg: rg = row-group (16 rows), tg picks
// n-tiles t12 = tg*6..tg*6+5.  Per kc a 12 KB weight chunk is staged once
// into LDS (reg double-buffer), shared by all 4 waves -> weight reuse M=32.
// K and V written in MFMA-fragment-contiguous tile layout:
//   K elem (kv,h): ((kv>>6)*4+((kv>>4)&3))*2+(h>>5))*512
//                  + ((h>>3)&3)*128 + (kv&15)*8 + (h&7)
//   V elem (kv,h): ((kv>>6)*2+((kv>>5)&1))*4+(h>>4))*512
//                  + ((kv>>3)&3)*128 + (h&15)*8 + (kv&7)
// so attn's fragment loads are contiguous 1 KB per wave.
// ---------------------------------------------------------------------------
__global__ __launch_bounds__(256, 2) void qkv_proj_kernel(
    const float* __restrict__ x, const bf16_t* __restrict__ Wb,
    bf16_t* __restrict__ qg, bf16_t* __restrict__ kfr, bf16_t* __restrict__ vfr)
{
  __shared__ __align__(16) bf16_t wch[6144];   // 12 KB chunk

  const int tid  = threadIdx.x;
  const int lane = tid & 63;
  const int wave = tid >> 6;
  const int mr   = lane & 15;
  const int quad = lane >> 4;
  const int rg   = wave >> 1;
  const int tg   = wave & 1;
  const int m0   = blockIdx.x * 32;

  floatx4 acc[6];
#pragma unroll
  for (int i = 0; i < 6; ++i) acc[i] = (floatx4){0.f, 0.f, 0.f, 0.f};

  const float* xp = x + (size_t)(m0 + rg * 16 + mr) * CD + quad * 8;

  // preload chunk 0 (regs) and x(0)
  bf16x8 wreg[3];
#pragma unroll
  for (int i = 0; i < 3; ++i)
    wreg[i] = *(const bf16x8*)(Wb + i * 2048 + tid * 8);
  float4 xa = *(const float4*)xp;
  float4 xb = *(const float4*)(xp + 4);

  for (int kc = 0; kc < 32; ++kc) {
    if (kc) __syncthreads();           // prior chunk reads done
#pragma unroll
    for (int i = 0; i < 3; ++i)
      *(bf16x8*)&wch[i * 2048 + tid * 8] = wreg[i];
    bf16x8 af;
    af[0]=(bf16_t)xa.x; af[1]=(bf16_t)xa.y; af[2]=(bf16_t)xa.z; af[3]=(bf16_t)xa.w;
    af[4]=(bf16_t)xb.x; af[5]=(bf16_t)xb.y; af[6]=(bf16_t)xb.z; af[7]=(bf16_t)xb.w;
    __syncthreads();                   // chunk kc visible
    if (kc < 31) {                     // prefetch kc+1 (overlaps the MFMAs)
#pragma unroll
      for (int i = 0; i < 3; ++i)
        wreg[i] = *(const bf16x8*)(Wb + (kc + 1) * 6144 + i * 2048 + tid * 8);
      xa = *(const float4*)(xp + (kc + 1) * 32);
      xb = *(const float4*)(xp + (kc + 1) * 32 + 4);
    }
#pragma unroll
    for (int i = 0; i < 6; ++i) {
      bf16x8 wf = *(bf16x8*)&wch[(tg * 6 + i) * 512 + lane * 8];
      acc[i] = __builtin_amdgcn_mfma_f32_16x16x32_bf16(af, wf, acc[i], 0, 0, 0);
    }
  }

  // ---- epilogue.  C/D: row = quad*4+reg (m -> trow), col = mr (n -> h) ----
  const float qscale = 0.18033688011112042f;  // 0.125 * log2(e)
#pragma unroll
  for (int i = 0; i < 6; ++i) {
    const int t12  = tg * 6 + i;
    const int wsel = t12 >> 2;
    const int nt   = t12 & 3;
#pragma unroll
    for (int r = 0; r < 4; ++r) {
      const int trow = m0 + rg * 16 + quad * 4 + r;
      const int h    = nt * 16 + mr;
      const float v  = acc[i][r];
      if (wsel == 0) {
        qg[(size_t)trow * HSZ + h] = (bf16_t)(v * qscale);
      } else if (wsel == 1) {
        const size_t a = ((((size_t)(trow >> 6)) * 4 + ((trow >> 4) & 3)) * 2
                          + (h >> 5)) * 512
                         + ((h >> 3) & 3) * 128 + (trow & 15) * 8 + (h & 7);
        kfr[a] = (bf16_t)v;
      } else {
        const size_t a = ((((size_t)(trow >> 6)) * 2 + ((trow >> 5) & 1)) * 4
                          + (h >> 4)) * 512
                         + ((trow >> 3) & 3) * 128 + (h & 15) * 8 + (trow & 7);
        vfr[a] = (bf16_t)v;
      }
    }
  }
}

// ---------------------------------------------------------------------------
// Softmax over one S^T subtile.  Lane (mr,quad) holds, for q-row q=mr, the
// 16 scores kv = nt*16 + quad*4 + r in sv[nt][r]; the full 64-score row is
// spread over the 4 quads of the same mr.  Row max = in-lane tree + 2
// shfl_xor; l stays a per-lane partial (cross-quad summed once at combine).
// P^T written packed: bf16x4 per nt (kv-consecutive) -> 4 ds_write_b64.
// alpha==1 (no new max anywhere in the wave) skips the rescale exactly.
// ---------------------------------------------------------------------------
__device__ __forceinline__ void softmax_step(
    floatx4 (&sv)[4], float& mstv, float& lstv, floatx4 (&ov)[4],
    bf16_t* plp, const int mr, const int quad)
{
  float a = fmaxf(fmaxf(sv[0][0], sv[0][1]), fmaxf(sv[0][2], sv[0][3]));
  float b = fmaxf(fmaxf(sv[1][0], sv[1][1]), fmaxf(sv[1][2], sv[1][3]));
  float c = fmaxf(fmaxf(sv[2][0], sv[2][1]), fmaxf(sv[2][2], sv[2][3]));
  float d = fmaxf(fmaxf(sv[3][0], sv[3][1]), fmaxf(sv[3][2], sv[3][3]));
  float mx = fmaxf(fmaxf(a, b), fmaxf(c, d));
  mx = qmax(mx);
  const float mnew = fmaxf(mstv, mx);
  float rs = 0.f;
#pragma unroll
  for (int nt = 0; nt < 4; ++nt) {
    const float p0 = fexp2(sv[nt][0] - mnew);
    const float p1 = fexp2(sv[nt][1] - mnew);
    const float p2 = fexp2(sv[nt][2] - mnew);
    const float p3 = fexp2(sv[nt][3] - mnew);
    rs += (p0 + p1) + (p2 + p3);
    bf16x4 w;
    w[0] = (bf16_t)p0; w[1] = (bf16_t)p1; w[2] = (bf16_t)p2; w[3] = (bf16_t)p3;
    *(bf16x4*)(plp + mr * 72 + nt * 16 + quad * 4) = w;
  }
  if (__all(mx <= mstv)) {
    lstv += rs;                        // alpha == 1 exactly, skip rescale
  } else {
    const float alpha = fexp2(mstv - mnew);
    mstv = mnew;
    lstv = alpha * lstv + rs;
#pragma unroll
    for (int nt = 0; nt < 4; ++nt)
#pragma unroll
      for (int r = 0; r < 4; ++r) ov[nt][r] *= alpha;
  }
}

// ---------------------------------------------------------------------------
// Kernel 2: causal flash attention, S^T formulation.  256 blocks x 1024 thr
// (16 waves).  Block owns paired 32-row groups (gA=pr, gB=127-pr) of batch
// b = bid&3 (XCD-pinned K/V).  Waves partitioned between groups by KV work;
// each wave owns 32 q-rows (2 subtiles sharing all K/V loads).
//   S^T = mfma(K, Q):  col(lane&15)=q, row(quad*4+reg)=kv  -> softmax row
//   reductions are in-lane + 2 shfl_xor, P^T is kv-consecutive in regs.
//   O^T = mfma(V, P^T): col(lane&15)=q, row(quad*4+reg)=h within tile nt.
// ---------------------------------------------------------------------------
__global__ __launch_bounds__(1024, 4) void attn_kernel(
    const bf16_t* __restrict__ qg, const bf16_t* __restrict__ kfr,
    const bf16_t* __restrict__ vfr, float* __restrict__ out)
{
  __shared__ __align__(16) char smem[73728];            // plds U cmbo
  __shared__ float cml[16][16][2];
  bf16_t* plds = (bf16_t*)smem;                         // 16 x 2304 elems
  float (*cmbo)[16][68] = (float (*)[16][68])smem;      // [16][16][68]

  const int tid  = threadIdx.x;
  const int lane = tid & 63;
  const int wave = tid >> 6;     // 0..15
  const int mr   = lane & 15;
  const int quad = lane >> 4;

  const int bid = blockIdx.x;    // 0..255
  const int b   = bid & 3;
  const int pr  = bid >> 2;      // 0..63
  const int gA  = pr;
  const int gB  = 127 - pr;
  const int nAw = (gA >> 1) + 1;
  const int nBw = (gB >> 1) + 1;
  int na = (16 * nAw + ((nAw + nBw) >> 1)) / (nAw + nBw);
  na = na < 1 ? 1 : (na > 15 ? 15 : na);

  const bool inA   = wave < na;
  const int g      = inA ? gA : gB;
  const int slot   = inA ? wave : wave - na;
  const int nsplit = inA ? na : 16 - na;
  const int q0     = g * 32;
  const int ktmax  = g >> 1;

  const size_t baseq = (size_t)b * TT * HSZ;
  const bf16_t* kb = kfr + (size_t)b * 64 * 4096;   // 64 tiles x 4096 elems
  const bf16_t* vb = vfr + (size_t)b * 64 * 4096;

  bf16_t* pl0 = plds + wave * 2304;
  bf16_t* pl1 = pl0 + 1152;

  // Q fragments (used as MFMA B operand): lane&15 = q-row, elems = h
  bf16x8 qf[2][2];
#pragma unroll
  for (int s = 0; s < 2; ++s) {
    const bf16_t* qp = qg + baseq + (size_t)(q0 + s * 16 + mr) * HSZ + quad * 8;
    qf[s][0] = *(const bf16x8*)qp;
    qf[s][1] = *(const bf16x8*)(qp + 32);
  }

  floatx4 o0[4], o1[4];            // O^T: lane q=mr, h = nt*16+quad*4+r
#pragma unroll
  for (int i = 0; i < 4; ++i) {
    o0[i] = (floatx4){0.f, 0.f, 0.f, 0.f};
    o1[i] = (floatx4){0.f, 0.f, 0.f, 0.f};
  }
  float mst[2] = {NEG_BIG, NEG_BIG};   // per-lane row stats (row = mr)
  float lst[2] = {0.f, 0.f};           // per-lane PARTIAL row sum (16 kv)

  for (int kt = slot; kt <= ktmax; kt += nsplit) {
    const int k0 = kt * 64;

    // ---- S^T for both subtiles: mfma(K, Q).  K fragments = A operand ----
    floatx4 s0[4], s1[4];
#pragma unroll
    for (int i = 0; i < 4; ++i) {
      s0[i] = (floatx4){0.f, 0.f, 0.f, 0.f};
      s1[i] = (floatx4){0.f, 0.f, 0.f, 0.f};
    }
#pragma unroll
    for (int nt = 0; nt < 4; ++nt) {
      const bf16_t* kp = kb + ((size_t)kt * 4 + nt) * 1024 + lane * 8;
      bf16x8 kb0 = *(const bf16x8*)kp;          // h 0..31
      bf16x8 kb1 = *(const bf16x8*)(kp + 512);  // h 32..63
      s0[nt] = __builtin_amdgcn_mfma_f32_16x16x32_bf16(kb0, qf[0][0], s0[nt], 0, 0, 0);
      s0[nt] = __builtin_amdgcn_mfma_f32_16x16x32_bf16(kb1, qf[0][1], s0[nt], 0, 0, 0);
      s1[nt] = __builtin_amdgcn_mfma_f32_16x16x32_bf16(kb0, qf[1][0], s1[nt], 0, 0, 0);
      s1[nt] = __builtin_amdgcn_mfma_f32_16x16x32_bf16(kb1, qf[1][1], s1[nt], 0, 0, 0);
    }

    // ---- causal mask (last tile only): kv = k0+nt*16+quad*4+r, q = q0+mr ----
    if (kt == ktmax) {
      const int qa0 = q0 + mr;
#pragma unroll
      for (int nt = 0; nt < 4; ++nt) {
#pragma unroll
        for (int r = 0; r < 4; ++r) {
          const int kv = k0 + nt * 16 + quad * 4 + r;
          if (kv > qa0)      s0[nt][r] = NEG_BIG;
          if (kv > qa0 + 16) s1[nt][r] = NEG_BIG;
        }
      }
    }

    // ---- softmax subtile 0 -> P0^T (packed b64 stores) ----
    softmax_step(s0, mst[0], lst[0], o0, pl0, mr, quad);

    // ---- V fragment loads kc=0 (kv 0..31), contiguous 1 KB each ----
    bf16x8 vfa[4];
#pragma unroll
    for (int nt = 0; nt < 4; ++nt)
      vfa[nt] = *(const bf16x8*)(vb + ((size_t)kt * 8 + nt) * 512 + lane * 8);

    // ---- softmax subtile 1 -> P1^T ----
    softmax_step(s1, mst[1], lst[1], o1, pl1, mr, quad);

    bf16x8 vfb[4];                 // kc=1 (kv 32..63)
#pragma unroll
    for (int nt = 0; nt < 4; ++nt)
      vfb[nt] = *(const bf16x8*)(vb + ((size_t)kt * 8 + nt) * 512 + 2048 + lane * 8);

    // ---- O^T += V * P^T ----
    {
      bf16x8 pa0 = *(bf16x8*)&pl0[mr * 72 + quad * 8];
      bf16x8 pa1 = *(bf16x8*)&pl1[mr * 72 + quad * 8];
#pragma unroll
      for (int nt = 0; nt < 4; ++nt) {
        o0[nt] = __builtin_amdgcn_mfma_f32_16x16x32_bf16(vfa[nt], pa0, o0[nt], 0, 0, 0);
        o1[nt] = __builtin_amdgcn_mfma_f32_16x16x32_bf16(vfa[nt], pa1, o1[nt], 0, 0, 0);
      }
      bf16x8 pb0 = *(bf16x8*)&pl0[mr * 72 + 32 + quad * 8];
      bf16x8 pb1 = *(bf16x8*)&pl1[mr * 72 + 32 + quad * 8];
#pragma unroll
      for (int nt = 0; nt < 4; ++nt) {
        o0[nt] = __builtin_amdgcn_mfma_f32_16x16x32_bf16(vfb[nt], pb0, o0[nt], 0, 0, 0);
        o1[nt] = __builtin_amdgcn_mfma_f32_16x16x32_bf16(vfb[nt], pb1, o1[nt], 0, 0, 0);
      }
    }
  }

  // ---- combine: per group over its wave-slots, one subtile per pass ----
  __syncthreads();   // all PV reads of plds done (cmbo overlays it)
#pragma unroll
  for (int s = 0; s < 2; ++s) {
    const float lsum = qsum(lst[s]);   // cross-quad: full row sum
    if (lane < 16) {
      cml[wave][lane][0] = mst[s];
      cml[wave][lane][1] = lsum;
    }
    __syncthreads();
    {
      const int lo = inA ? 0 : na;
      const int hi = inA ? na : 16;
      float mstar = cml[lo][mr][0];
      for (int i = lo + 1; i < hi; ++i) mstar = fmaxf(mstar, cml[i][mr][0]);
      const float scale = fexp2(mst[s] - mstar);
#pragma unroll
      for (int nt = 0; nt < 4; ++nt) {
        floatx4 t;
#pragma unroll
        for (int r = 0; r < 4; ++r) t[r] = (s ? o1[nt][r] : o0[nt][r]) * scale;
        *(floatx4*)&cmbo[wave][mr][nt * 16 + quad * 4] = t;   // row=q, col=h
      }
    }
    __syncthreads();
    {
      const int grp = tid >> 9;            // 0 = A, 1 = B
      const int row = (tid >> 5) & 15;
      const int c0  = (tid & 31) * 2;
      const int lo  = grp ? na : 0;
      const int hi  = grp ? 16 : na;
      const int gq0 = (grp ? gB : gA) * 32 + s * 16;
      float mstar = cml[lo][row][0];
      for (int i = lo + 1; i < hi; ++i) mstar = fmaxf(mstar, cml[i][row][0]);
      float l = 0.f;
      for (int i = lo; i < hi; ++i)
        l += cml[i][row][1] * fexp2(cml[i][row][0] - mstar);
      float sx = 0.f, sy = 0.f;
      for (int i = lo; i < hi; ++i) {
        float2 v = *(float2*)&cmbo[i][row][c0];
        sx += v.x; sy += v.y;
      }
      const float invl = 1.0f / l;
      float2 res; res.x = sx * invl; res.y = sy * invl;
      *(float2*)(out + baseq + (size_t)(gq0 + row) * HSZ + c0) = res;
    }
    __syncthreads();   // cml/cmbo reused by next pass
  }
}

// ---------------------------------------------------------------------------
extern "C" void kernel_launch(void* const* d_in, const int* in_sizes, int n_in,
                              void* d_out, int out_size, void* d_ws, size_t ws_size,
                              hipStream_t stream) {
  const float* x  = (const float*)d_in[0];
  const float* Wk = (const float*)d_in[1];
  const float* Wq = (const float*)d_in[2];
  const float* Wv = (const float*)d_in[3];
  float* out = (float*)d_out;

  bf16_t* ws  = (bf16_t*)d_ws;
  bf16_t* Wb  = ws + WB_OFF;
  bf16_t* qg  = ws + Q_OFF;
  bf16_t* kfr = ws + K_OFF;
  bf16_t* vfr = ws + V_OFF;

  wcvt_kernel<<<dim3(192), dim3(256), 0, stream>>>(Wk, Wq, Wv, Wb);
  qkv_proj_kernel<<<dim3(512), dim3(256), 0, stream>>>(x, Wb, qg, kfr, vfr);
  attn_kernel<<<dim3(256), dim3(1024), 0, stream>>>(qg, kfr, vfr, out);
}

// Round 2
// 157.057 us; speedup vs baseline: 1.1506x; 1.0148x over previous
//
#include <hip/hip_runtime.h>
#include <math.h>

typedef __bf16 bf16_t;
typedef __bf16 bf16x8 __attribute__((ext_vector_type(8)));
typedef __bf16 bf16x4 __attribute__((ext_vector_type(4)));
typedef float  floatx4 __attribute__((ext_vector_type(4)));

#define TT   4096
#define CD   1024
#define HSZ  64
#define NROW 16384
#define NEG_BIG (-1e30f)

// workspace element offsets (bf16)
#define WB_OFF 0                       // [kc][t12][512]  = 196608 elems
#define Q_OFF  196608                  // q[row][64]
#define K_OFF  (196608 + NROW * HSZ)   // K fragment tiles
#define V_OFF  (196608 + 2 * NROW * HSZ) // V fragment tiles

#if __has_builtin(__builtin_amdgcn_exp2f)
__device__ __forceinline__ float fexp2(float x) { return __builtin_amdgcn_exp2f(x); }
#else
__device__ __forceinline__ float fexp2(float x) { return exp2f(x); }
#endif

// cross-quad (lane ^16, ^32) reductions: a q-row's data lives on 4 lanes
__device__ __forceinline__ float qmax(float v) {
  v = fmaxf(v, __shfl_xor(v, 16));
  v = fmaxf(v, __shfl_xor(v, 32));
  return v;
}
__device__ __forceinline__ float qsum(float v) {
  v += __shfl_xor(v, 16);
  v += __shfl_xor(v, 32);
  return v;
}

// ---------------------------------------------------------------------------
// Kernel 0: fp32 weights -> bf16, layout [kc][t12][512] so a proj block's
// per-kc chunk (all 12 n-tiles' fragments) is one contiguous 12 KB.
// Fragment elem (lane,j) = W_wsel[n = nt*16+(lane&15)][k = kc*32+(lane>>4)*8+j].
// ---------------------------------------------------------------------------
__global__ __launch_bounds__(256, 1) void wcvt_kernel(
    const float* __restrict__ Wk, const float* __restrict__ Wq,
    const float* __restrict__ Wv, bf16_t* __restrict__ Wb)
{
  const int t    = blockIdx.x * 256 + threadIdx.x;  // 192 blocks
  const int e    = t * 4;
  const int tile = e >> 9;          // 0..383
  const int kc   = tile / 12;
  const int t12  = tile - kc * 12;
  const int r    = e & 511;
  const int lane = r >> 3;
  const int j0   = r & 7;
  const int wsel = t12 >> 2;
  const int nt   = t12 & 3;
  const int n    = nt * 16 + (lane & 15);
  const int k    = kc * 32 + (lane >> 4) * 8 + j0;
  const float* src = (wsel == 0) ? Wq : (wsel == 1) ? Wk : Wv;
  float4 f = *(const float4*)(src + n * CD + k);
  bf16x4 o;
  o[0] = (bf16_t)f.x; o[1] = (bf16_t)f.y; o[2] = (bf16_t)f.z; o[3] = (bf16_t)f.w;
  *(bf16x4*)(Wb + e) = o;
}

// ---------------------------------------------------------------------------
// Kernel 1: QKV projection.  512 blocks x 512 threads (8 waves); block owns
// 32 x-rows.  wave = rg*4+tg: rg = row-group (16 rows), tg owns 3 n-tiles
// t12 = tg*3..tg*3+2.  kc processed in PAIRS: one 24 KB LDS stage per 2
// K-steps (31 barriers total), register double-buffered prefetch, so each
// stage's global loads have 12 MFMAs + 12 ds_read_b128 per wave to hide
// under, with 16 waves/CU (launch_bounds(512,4), 2 blocks/CU, all-resident).
// K and V written in MFMA-fragment-contiguous tile layout:
//   K elem (kv,h): ((kv>>6)*4+((kv>>4)&3))*2+(h>>5))*512
//                  + ((h>>3)&3)*128 + (kv&15)*8 + (h&7)
//   V elem (kv,h): ((kv>>6)*2+((kv>>5)&1))*4+(h>>4))*512
//                  + ((kv>>3)&3)*128 + (h&15)*8 + (kv&7)
// so attn's fragment loads are contiguous 1 KB per wave.
// ---------------------------------------------------------------------------
__global__ __launch_bounds__(512, 4) void qkv_proj_kernel(
    const float* __restrict__ x, const bf16_t* __restrict__ Wb,
    bf16_t* __restrict__ qg, bf16_t* __restrict__ kfr, bf16_t* __restrict__ vfr)
{
  __shared__ __align__(16) bf16_t wch[12288];   // 24 KB kc-pair chunk

  const int tid  = threadIdx.x;     // 0..511
  const int lane = tid & 63;
  const int wave = tid >> 6;        // 0..7
  const int mr   = lane & 15;
  const int quad = lane >> 4;
  const int rg   = wave >> 2;       // 0..1: row group
  const int tg   = wave & 3;        // 0..3: tile group (3 t12 tiles)
  const int m0   = blockIdx.x * 32;

  floatx4 acc[3];
#pragma unroll
  for (int i = 0; i < 3; ++i) acc[i] = (floatx4){0.f, 0.f, 0.f, 0.f};

  const float* xp = x + (size_t)(m0 + rg * 16 + mr) * CD + quad * 8;

  // preload pair-chunk 0 (regs) and x cols 0..63 of this lane's row
  bf16x8 wreg[3];
#pragma unroll
  for (int i = 0; i < 3; ++i)
    wreg[i] = *(const bf16x8*)(Wb + i * 4096 + tid * 8);
  float4 xv0 = *(const float4*)(xp);
  float4 xv1 = *(const float4*)(xp + 4);
  float4 xv2 = *(const float4*)(xp + 32);
  float4 xv3 = *(const float4*)(xp + 36);

  for (int u = 0; u < 16; ++u) {         // kc pair: kc = 2u, 2u+1
    if (u) __syncthreads();              // prior chunk reads done
#pragma unroll
    for (int i = 0; i < 3; ++i)
      *(bf16x8*)&wch[i * 4096 + tid * 8] = wreg[i];
    bf16x8 afe, afo;
    afe[0]=(bf16_t)xv0.x; afe[1]=(bf16_t)xv0.y; afe[2]=(bf16_t)xv0.z; afe[3]=(bf16_t)xv0.w;
    afe[4]=(bf16_t)xv1.x; afe[5]=(bf16_t)xv1.y; afe[6]=(bf16_t)xv1.z; afe[7]=(bf16_t)xv1.w;
    afo[0]=(bf16_t)xv2.x; afo[1]=(bf16_t)xv2.y; afo[2]=(bf16_t)xv2.z; afo[3]=(bf16_t)xv2.w;
    afo[4]=(bf16_t)xv3.x; afo[5]=(bf16_t)xv3.y; afo[6]=(bf16_t)xv3.z; afo[7]=(bf16_t)xv3.w;
    __syncthreads();                     // chunk u visible
    if (u < 15) {                        // prefetch pair u+1 (hides under MFMAs)
#pragma unroll
      for (int i = 0; i < 3; ++i)
        wreg[i] = *(const bf16x8*)(Wb + (u + 1) * 12288 + i * 4096 + tid * 8);
      xv0 = *(const float4*)(xp + (u + 1) * 64);
      xv1 = *(const float4*)(xp + (u + 1) * 64 + 4);
      xv2 = *(const float4*)(xp + (u + 1) * 64 + 32);
      xv3 = *(const float4*)(xp + (u + 1) * 64 + 36);
    }
#pragma unroll
    for (int i = 0; i < 3; ++i) {
      bf16x8 wf = *(bf16x8*)&wch[(tg * 3 + i) * 512 + lane * 8];
      acc[i] = __builtin_amdgcn_mfma_f32_16x16x32_bf16(afe, wf, acc[i], 0, 0, 0);
    }
#pragma unroll
    for (int i = 0; i < 3; ++i) {
      bf16x8 wf = *(bf16x8*)&wch[6144 + (tg * 3 + i) * 512 + lane * 8];
      acc[i] = __builtin_amdgcn_mfma_f32_16x16x32_bf16(afo, wf, acc[i], 0, 0, 0);
    }
  }

  // ---- epilogue.  C/D: row = quad*4+reg (m -> trow), col = mr (n -> h) ----
  const float qscale = 0.18033688011112042f;  // 0.125 * log2(e)
#pragma unroll
  for (int i = 0; i < 3; ++i) {
    const int t12  = tg * 3 + i;
    const int wsel = t12 >> 2;
    const int nt   = t12 & 3;
#pragma unroll
    for (int r = 0; r < 4; ++r) {
      const int trow = m0 + rg * 16 + quad * 4 + r;
      const int h    = nt * 16 + mr;
      const float v  = acc[i][r];
      if (wsel == 0) {
        qg[(size_t)trow * HSZ + h] = (bf16_t)(v * qscale);
      } else if (wsel == 1) {
        const size_t a = ((((size_t)(trow >> 6)) * 4 + ((trow >> 4) & 3)) * 2
                          + (h >> 5)) * 512
                         + ((h >> 3) & 3) * 128 + (trow & 15) * 8 + (h & 7);
        kfr[a] = (bf16_t)v;
      } else {
        const size_t a = ((((size_t)(trow >> 6)) * 2 + ((trow >> 5) & 1)) * 4
                          + (h >> 4)) * 512
                         + ((trow >> 3) & 3) * 128 + (h & 15) * 8 + (trow & 7);
        vfr[a] = (bf16_t)v;
      }
    }
  }
}

// ---------------------------------------------------------------------------
// Softmax over one S^T subtile.  Lane (mr,quad) holds, for q-row q=mr, the
// 16 scores kv = nt*16 + quad*4 + r in sv[nt][r]; the full 64-score row is
// spread over the 4 quads of the same mr.  Row max = in-lane tree + 2
// shfl_xor; l stays a per-lane partial (cross-quad summed once at combine).
// P^T written packed: bf16x4 per nt (kv-consecutive) -> 4 ds_write_b64.
// alpha==1 (no new max anywhere in the wave) skips the rescale exactly.
// ---------------------------------------------------------------------------
__device__ __forceinline__ void softmax_step(
    floatx4 (&sv)[4], float& mstv, float& lstv, floatx4 (&ov)[4],
    bf16_t* plp, const int mr, const int quad)
{
  float a = fmaxf(fmaxf(sv[0][0], sv[0][1]), fmaxf(sv[0][2], sv[0][3]));
  float b = fmaxf(fmaxf(sv[1][0], sv[1][1]), fmaxf(sv[1][2], sv[1][3]));
  float c = fmaxf(fmaxf(sv[2][0], sv[2][1]), fmaxf(sv[2][2], sv[2][3]));
  float d = fmaxf(fmaxf(sv[3][0], sv[3][1]), fmaxf(sv[3][2], sv[3][3]));
  float mx = fmaxf(fmaxf(a, b), fmaxf(c, d));
  mx = qmax(mx);
  const float mnew = fmaxf(mstv, mx);
  float rs = 0.f;
#pragma unroll
  for (int nt = 0; nt < 4; ++nt) {
    const float p0 = fexp2(sv[nt][0] - mnew);
    const float p1 = fexp2(sv[nt][1] - mnew);
    const float p2 = fexp2(sv[nt][2] - mnew);
    const float p3 = fexp2(sv[nt][3] - mnew);
    rs += (p0 + p1) + (p2 + p3);
    bf16x4 w;
    w[0] = (bf16_t)p0; w[1] = (bf16_t)p1; w[2] = (bf16_t)p2; w[3] = (bf16_t)p3;
    *(bf16x4*)(plp + mr * 72 + nt * 16 + quad * 4) = w;
  }
  if (__all(mx <= mstv)) {
    lstv += rs;                        // alpha == 1 exactly, skip rescale
  } else {
    const float alpha = fexp2(mstv - mnew);
    mstv = mnew;
    lstv = alpha * lstv + rs;
#pragma unroll
    for (int nt = 0; nt < 4; ++nt)
#pragma unroll
      for (int r = 0; r < 4; ++r) ov[nt][r] *= alpha;
  }
}

// ---------------------------------------------------------------------------
// Kernel 2: causal flash attention, S^T formulation.  256 blocks x 1024 thr
// (16 waves).  Block owns paired 32-row groups (gA=pr, gB=127-pr) of batch
// b = bid&3 (XCD-pinned K/V).  Waves partitioned between groups by KV work;
// each wave owns 32 q-rows (2 subtiles sharing all K/V loads).
//   S^T = mfma(K, Q):  col(lane&15)=q, row(quad*4+reg)=kv  -> softmax row
//   reductions are in-lane + 2 shfl_xor, P^T is kv-consecutive in regs.
//   O^T = mfma(V, P^T): col(lane&15)=q, row(quad*4+reg)=h within tile nt.
// ---------------------------------------------------------------------------
__global__ __launch_bounds__(1024, 4) void attn_kernel(
    const bf16_t* __restrict__ qg, const bf16_t* __restrict__ kfr,
    const bf16_t* __restrict__ vfr, float* __restrict__ out)
{
  __shared__ __align__(16) char smem[73728];            // plds U cmbo
  __shared__ float cml[16][16][2];
  bf16_t* plds = (bf16_t*)smem;                         // 16 x 2304 elems
  float (*cmbo)[16][68] = (float (*)[16][68])smem;      // [16][16][68]

  const int tid  = threadIdx.x;
  const int lane = tid & 63;
  const int wave = tid >> 6;     // 0..15
  const int mr   = lane & 15;
  const int quad = lane >> 4;

  const int bid = blockIdx.x;    // 0..255
  const int b   = bid & 3;
  const int pr  = bid >> 2;      // 0..63
  const int gA  = pr;
  const int gB  = 127 - pr;
  const int nAw = (gA >> 1) + 1;
  const int nBw = (gB >> 1) + 1;
  int na = (16 * nAw + ((nAw + nBw) >> 1)) / (nAw + nBw);
  na = na < 1 ? 1 : (na > 15 ? 15 : na);

  const bool inA   = wave < na;
  const int g      = inA ? gA : gB;
  const int slot   = inA ? wave : wave - na;
  const int nsplit = inA ? na : 16 - na;
  const int q0     = g * 32;
  const int ktmax  = g >> 1;

  const size_t baseq = (size_t)b * TT * HSZ;
  const bf16_t* kb = kfr + (size_t)b * 64 * 4096;   // 64 tiles x 4096 elems
  const bf16_t* vb = vfr + (size_t)b * 64 * 4096;

  bf16_t* pl0 = plds + wave * 2304;
  bf16_t* pl1 = pl0 + 1152;

  // Q fragments (used as MFMA B operand): lane&15 = q-row, elems = h
  bf16x8 qf[2][2];
#pragma unroll
  for (int s = 0; s < 2; ++s) {
    const bf16_t* qp = qg + baseq + (size_t)(q0 + s * 16 + mr) * HSZ + quad * 8;
    qf[s][0] = *(const bf16x8*)qp;
    qf[s][1] = *(const bf16x8*)(qp + 32);
  }

  floatx4 o0[4], o1[4];            // O^T: lane q=mr, h = nt*16+quad*4+r
#pragma unroll
  for (int i = 0; i < 4; ++i) {
    o0[i] = (floatx4){0.f, 0.f, 0.f, 0.f};
    o1[i] = (floatx4){0.f, 0.f, 0.f, 0.f};
  }
  float mst[2] = {NEG_BIG, NEG_BIG};   // per-lane row stats (row = mr)
  float lst[2] = {0.f, 0.f};           // per-lane PARTIAL row sum (16 kv)

  for (int kt = slot; kt <= ktmax; kt += nsplit) {
    const int k0 = kt * 64;

    // ---- S^T for both subtiles: mfma(K, Q).  K fragments = A operand ----
    floatx4 s0[4], s1[4];
#pragma unroll
    for (int i = 0; i < 4; ++i) {
      s0[i] = (floatx4){0.f, 0.f, 0.f, 0.f};
      s1[i] = (floatx4){0.f, 0.f, 0.f, 0.f};
    }
#pragma unroll
    for (int nt = 0; nt < 4; ++nt) {
      const bf16_t* kp = kb + ((size_t)kt * 4 + nt) * 1024 + lane * 8;
      bf16x8 kb0 = *(const bf16x8*)kp;          // h 0..31
      bf16x8 kb1 = *(const bf16x8*)(kp + 512);  // h 32..63
      s0[nt] = __builtin_amdgcn_mfma_f32_16x16x32_bf16(kb0, qf[0][0], s0[nt], 0, 0, 0);
      s0[nt] = __builtin_amdgcn_mfma_f32_16x16x32_bf16(kb1, qf[0][1], s0[nt], 0, 0, 0);
      s1[nt] = __builtin_amdgcn_mfma_f32_16x16x32_bf16(kb0, qf[1][0], s1[nt], 0, 0, 0);
      s1[nt] = __builtin_amdgcn_mfma_f32_16x16x32_bf16(kb1, qf[1][1], s1[nt], 0, 0, 0);
    }

    // ---- causal mask (last tile only): kv = k0+nt*16+quad*4+r, q = q0+mr ----
    if (kt == ktmax) {
      const int qa0 = q0 + mr;
#pragma unroll
      for (int nt = 0; nt < 4; ++nt) {
#pragma unroll
        for (int r = 0; r < 4; ++r) {
          const int kv = k0 + nt * 16 + quad * 4 + r;
          if (kv > qa0)      s0[nt][r] = NEG_BIG;
          if (kv > qa0 + 16) s1[nt][r] = NEG_BIG;
        }
      }
    }

    // ---- softmax subtile 0 -> P0^T (packed b64 stores) ----
    softmax_step(s0, mst[0], lst[0], o0, pl0, mr, quad);

    // ---- V fragment loads kc=0 (kv 0..31), contiguous 1 KB each ----
    bf16x8 vfa[4];
#pragma unroll
    for (int nt = 0; nt < 4; ++nt)
      vfa[nt] = *(const bf16x8*)(vb + ((size_t)kt * 8 + nt) * 512 + lane * 8);

    // ---- softmax subtile 1 -> P1^T ----
    softmax_step(s1, mst[1], lst[1], o1, pl1, mr, quad);

    bf16x8 vfb[4];                 // kc=1 (kv 32..63)
#pragma unroll
    for (int nt = 0; nt < 4; ++nt)
      vfb[nt] = *(const bf16x8*)(vb + ((size_t)kt * 8 + nt) * 512 + 2048 + lane * 8);

    // ---- O^T += V * P^T ----
    {
      bf16x8 pa0 = *(bf16x8*)&pl0[mr * 72 + quad * 8];
      bf16x8 pa1 = *(bf16x8*)&pl1[mr * 72 + quad * 8];
#pragma unroll
      for (int nt = 0; nt < 4; ++nt) {
        o0[nt] = __builtin_amdgcn_mfma_f32_16x16x32_bf16(vfa[nt], pa0, o0[nt], 0, 0, 0);
        o1[nt] = __builtin_amdgcn_mfma_f32_16x16x32_bf16(vfa[nt], pa1, o1[nt], 0, 0, 0);
      }
      bf16x8 pb0 = *(bf16x8*)&pl0[mr * 72 + 32 + quad * 8];
      bf16x8 pb1 = *(bf16x8*)&pl1[mr * 72 + 32 + quad * 8];
#pragma unroll
      for (int nt = 0; nt < 4; ++nt) {
        o0[nt] = __builtin_amdgcn_mfma_f32_16x16x32_bf16(vfb[nt], pb0, o0[nt], 0, 0, 0);
        o1[nt] = __builtin_amdgcn_mfma_f32_16x16x32_bf16(vfb[nt], pb1, o1[nt], 0, 0, 0);
      }
    }
  }

  // ---- combine: per group over its wave-slots, one subtile per pass ----
  __syncthreads();   // all PV reads of plds done (cmbo overlays it)
#pragma unroll
  for (int s = 0; s < 2; ++s) {
    const float lsum = qsum(lst[s]);   // cross-quad: full row sum
    if (lane < 16) {
      cml[wave][lane][0] = mst[s];
      cml[wave][lane][1] = lsum;
    }
    __syncthreads();
    {
      const int lo = inA ? 0 : na;
      const int hi = inA ? na : 16;
      float mstar = cml[lo][mr][0];
      for (int i = lo + 1; i < hi; ++i) mstar = fmaxf(mstar, cml[i][mr][0]);
      const float scale = fexp2(mst[s] - mstar);
#pragma unroll
      for (int nt = 0; nt < 4; ++nt) {
        floatx4 t;
#pragma unroll
        for (int r = 0; r < 4; ++r) t[r] = (s ? o1[nt][r] : o0[nt][r]) * scale;
        *(floatx4*)&cmbo[wave][mr][nt * 16 + quad * 4] = t;   // row=q, col=h
      }
    }
    __syncthreads();
    {
      const int grp = tid >> 9;            // 0 = A, 1 = B
      const int row = (tid >> 5) & 15;
      const int c0  = (tid & 31) * 2;
      const int lo  = grp ? na : 0;
      const int hi  = grp ? 16 : na;
      const int gq0 = (grp ? gB : gA) * 32 + s * 16;
      float mstar = cml[lo][row][0];
      for (int i = lo + 1; i < hi; ++i) mstar = fmaxf(mstar, cml[i][row][0]);
      float l = 0.f;
      for (int i = lo; i < hi; ++i)
        l += cml[i][row][1] * fexp2(cml[i][row][0] - mstar);
      float sx = 0.f, sy = 0.f;
      for (int i = lo; i < hi; ++i) {
        float2 v = *(float2*)&cmbo[i][row][c0];
        sx += v.x; sy += v.y;
      }
      const float invl = 1.0f / l;
      float2 res; res.x = sx * invl; res.y = sy * invl;
      *(float2*)(out + baseq + (size_t)(gq0 + row) * HSZ + c0) = res;
    }
    __syncthreads();   // cml/cmbo reused by next pass
  }
}

// ---------------------------------------------------------------------------
extern "C" void kernel_launch(void* const* d_in, const int* in_sizes, int n_in,
                              void* d_out, int out_size, void* d_ws, size_t ws_size,
                              hipStream_t stream) {
  const float* x  = (const float*)d_in[0];
  const float* Wk = (const float*)d_in[1];
  const float* Wq = (const float*)d_in[2];
  const float* Wv = (const float*)d_in[3];
  float* out = (float*)d_out;

  bf16_t* ws  = (bf16_t*)d_ws;
  bf16_t* Wb  = ws + WB_OFF;
  bf16_t* qg  = ws + Q_OFF;
  bf16_t* kfr = ws + K_OFF;
  bf16_t* vfr = ws + V_OFF;

  wcvt_kernel<<<dim3(192), dim3(256), 0, stream>>>(Wk, Wq, Wv, Wb);
  qkv_proj_kernel<<<dim3(512), dim3(512), 0, stream>>>(x, Wb, qg, kfr, vfr);
  attn_kernel<<<dim3(256), dim3(1024), 0, stream>>>(qg, kfr, vfr, out);
}

// Round 3
// 143.320 us; speedup vs baseline: 1.2609x; 1.0959x over previous
//
#include <hip/hip_runtime.h>
#include <math.h>

typedef __bf16 bf16_t;
typedef __bf16 bf16x8 __attribute__((ext_vector_type(8)));
typedef __bf16 bf16x4 __attribute__((ext_vector_type(4)));
typedef float  floatx4 __attribute__((ext_vector_type(4)));

#define TT   4096
#define CD   1024
#define HSZ  64
#define NROW 16384
#define NEG_BIG (-1e30f)

// workspace element offsets (bf16)
#define WB_OFF 0                       // [kc][t12][512]  = 196608 elems
#define Q_OFF  196608                  // q[row][64]
#define K_OFF  (196608 + NROW * HSZ)   // K fragment tiles
#define V_OFF  (196608 + 2 * NROW * HSZ) // V fragment tiles

#if __has_builtin(__builtin_amdgcn_exp2f)
__device__ __forceinline__ float fexp2(float x) { return __builtin_amdgcn_exp2f(x); }
#else
__device__ __forceinline__ float fexp2(float x) { return exp2f(x); }
#endif

// cross-quad (lane ^16, ^32) reductions: a q-row's data lives on 4 lanes
__device__ __forceinline__ float qmax(float v) {
  v = fmaxf(v, __shfl_xor(v, 16));
  v = fmaxf(v, __shfl_xor(v, 32));
  return v;
}
__device__ __forceinline__ float qsum(float v) {
  v += __shfl_xor(v, 16);
  v += __shfl_xor(v, 32);
  return v;
}

// ---------------------------------------------------------------------------
// Kernel 0: fp32 weights -> bf16, layout [kc][t12][512] so a w-fragment for
// (kc, t12) is one contiguous 1 KB.
// Fragment elem (lane,j) = W_wsel[n = nt*16+(lane&15)][k = kc*32+(lane>>4)*8+j].
// ---------------------------------------------------------------------------
__global__ __launch_bounds__(256, 1) void wcvt_kernel(
    const float* __restrict__ Wk, const float* __restrict__ Wq,
    const float* __restrict__ Wv, bf16_t* __restrict__ Wb)
{
  const int t    = blockIdx.x * 256 + threadIdx.x;  // 192 blocks
  const int e    = t * 4;
  const int tile = e >> 9;          // 0..383
  const int kc   = tile / 12;
  const int t12  = tile - kc * 12;
  const int r    = e & 511;
  const int lane = r >> 3;
  const int j0   = r & 7;
  const int wsel = t12 >> 2;
  const int nt   = t12 & 3;
  const int n    = nt * 16 + (lane & 15);
  const int k    = kc * 32 + (lane >> 4) * 8 + j0;
  const float* src = (wsel == 0) ? Wq : (wsel == 1) ? Wk : Wv;
  float4 f = *(const float4*)(src + n * CD + k);
  bf16x4 o;
  o[0] = (bf16_t)f.x; o[1] = (bf16_t)f.y; o[2] = (bf16_t)f.z; o[3] = (bf16_t)f.w;
  *(bf16x4*)(Wb + e) = o;
}

// ---------------------------------------------------------------------------
// Kernel 1: QKV projection, BARRIER-FREE streaming form.  512 blocks x 256
// threads (4 waves).  Block owns 32 x-rows (2 m-tiles); wave kh = tid>>6 owns
// the K-quarter kc = kh*8..kh*8+7.  No LDS staging in the loop: each wave
// loads its x fragments (rows read exactly once grid-wide) and W fragments
// (1 KB contiguous, L1/L2-resident, reused for both m-tiles) directly from
// global and issues 24 MFMAs per kc.  Waves free-run -> loads stream with
// deep queues instead of the barrier-locked ~10% duty cycle that pinned the
// staged version at 1.4 TB/s.  End: 4-way partial-sum combine via LDS (3
// barriers total), wave kh=0 does the epilogue stores.
// K and V written in MFMA-fragment-contiguous tile layout (see attn).
// ---------------------------------------------------------------------------
__global__ __launch_bounds__(256, 2) void qkv_proj_kernel(
    const float* __restrict__ x, const bf16_t* __restrict__ Wb,
    bf16_t* __restrict__ qg, bf16_t* __restrict__ kfr, bf16_t* __restrict__ vfr)
{
  __shared__ __align__(16) floatx4 red[3][24][64];   // 72 KB combine buffer

  const int tid  = threadIdx.x;     // 0..255
  const int lane = tid & 63;
  const int kh   = tid >> 6;        // 0..3: K-quarter
  const int mr   = lane & 15;
  const int quad = lane >> 4;
  const int rt   = blockIdx.x;      // 0..511: 32-row group

  floatx4 acc[2][12];
#pragma unroll
  for (int mt = 0; mt < 2; ++mt)
#pragma unroll
    for (int i = 0; i < 12; ++i) acc[mt][i] = (floatx4){0.f, 0.f, 0.f, 0.f};

  const float* xp0 = x + (size_t)(rt * 32 + mr) * CD + quad * 8;
  const float* xp1 = xp0 + 16 * CD;

  for (int kc = kh * 8; kc < kh * 8 + 8; ++kc) {
    float4 a0 = *(const float4*)(xp0 + kc * 32);
    float4 a1 = *(const float4*)(xp0 + kc * 32 + 4);
    float4 b0 = *(const float4*)(xp1 + kc * 32);
    float4 b1 = *(const float4*)(xp1 + kc * 32 + 4);
    bf16x8 af0, af1;
    af0[0]=(bf16_t)a0.x; af0[1]=(bf16_t)a0.y; af0[2]=(bf16_t)a0.z; af0[3]=(bf16_t)a0.w;
    af0[4]=(bf16_t)a1.x; af0[5]=(bf16_t)a1.y; af0[6]=(bf16_t)a1.z; af0[7]=(bf16_t)a1.w;
    af1[0]=(bf16_t)b0.x; af1[1]=(bf16_t)b0.y; af1[2]=(bf16_t)b0.z; af1[3]=(bf16_t)b0.w;
    af1[4]=(bf16_t)b1.x; af1[5]=(bf16_t)b1.y; af1[6]=(bf16_t)b1.z; af1[7]=(bf16_t)b1.w;
    const bf16_t* wp = Wb + kc * 6144 + lane * 8;
#pragma unroll
    for (int i = 0; i < 12; ++i) {
      bf16x8 wf = *(const bf16x8*)(wp + i * 512);
      acc[0][i] = __builtin_amdgcn_mfma_f32_16x16x32_bf16(af0, wf, acc[0][i], 0, 0, 0);
      acc[1][i] = __builtin_amdgcn_mfma_f32_16x16x32_bf16(af1, wf, acc[1][i], 0, 0, 0);
    }
  }

  // ---- 4-way K-partial combine via LDS ----
  if (kh != 0) {
#pragma unroll
    for (int mt = 0; mt < 2; ++mt)
#pragma unroll
      for (int i = 0; i < 12; ++i)
        red[kh - 1][mt * 12 + i][lane] = acc[mt][i];
  }
  __syncthreads();
  if (kh == 0) {
    // ---- epilogue.  C/D: row = quad*4+reg (m -> trow), col = mr (n -> h) ----
    const float qscale = 0.18033688011112042f;  // 0.125 * log2(e)
#pragma unroll
    for (int mt = 0; mt < 2; ++mt) {
#pragma unroll
      for (int i = 0; i < 12; ++i) {
        floatx4 a = acc[mt][i];
        a += red[0][mt * 12 + i][lane];
        a += red[1][mt * 12 + i][lane];
        a += red[2][mt * 12 + i][lane];
        const int wsel = i >> 2;
        const int nt   = i & 3;
#pragma unroll
        for (int r = 0; r < 4; ++r) {
          const int trow = rt * 32 + mt * 16 + quad * 4 + r;
          const int h    = nt * 16 + mr;
          const float v  = a[r];
          if (wsel == 0) {
            qg[(size_t)trow * HSZ + h] = (bf16_t)(v * qscale);
          } else if (wsel == 1) {
            const size_t adr = ((((size_t)(trow >> 6)) * 4 + ((trow >> 4) & 3)) * 2
                                + (h >> 5)) * 512
                               + ((h >> 3) & 3) * 128 + (trow & 15) * 8 + (h & 7);
            kfr[adr] = (bf16_t)v;
          } else {
            const size_t adr = ((((size_t)(trow >> 6)) * 2 + ((trow >> 5) & 1)) * 4
                                + (h >> 4)) * 512
                               + ((trow >> 3) & 3) * 128 + (h & 15) * 8 + (trow & 7);
            vfr[adr] = (bf16_t)v;
          }
        }
      }
    }
  }
}

// ---------------------------------------------------------------------------
// Softmax over one S^T subtile.  Lane (mr,quad) holds, for q-row q=mr, the
// 16 scores kv = nt*16 + quad*4 + r in sv[nt][r]; the full 64-score row is
// spread over the 4 quads of the same mr.  Row max = in-lane tree + 2
// shfl_xor; l stays a per-lane partial (cross-quad summed once at combine).
// P^T written packed: bf16x4 per nt (kv-consecutive) -> 4 ds_write_b64.
// alpha==1 (no new max anywhere in the wave) skips the rescale exactly.
// ---------------------------------------------------------------------------
__device__ __forceinline__ void softmax_step(
    floatx4 (&sv)[4], float& mstv, float& lstv, floatx4 (&ov)[4],
    bf16_t* plp, const int mr, const int quad)
{
  float a = fmaxf(fmaxf(sv[0][0], sv[0][1]), fmaxf(sv[0][2], sv[0][3]));
  float b = fmaxf(fmaxf(sv[1][0], sv[1][1]), fmaxf(sv[1][2], sv[1][3]));
  float c = fmaxf(fmaxf(sv[2][0], sv[2][1]), fmaxf(sv[2][2], sv[2][3]));
  float d = fmaxf(fmaxf(sv[3][0], sv[3][1]), fmaxf(sv[3][2], sv[3][3]));
  float mx = fmaxf(fmaxf(a, b), fmaxf(c, d));
  mx = qmax(mx);
  const float mnew = fmaxf(mstv, mx);
  float rs = 0.f;
#pragma unroll
  for (int nt = 0; nt < 4; ++nt) {
    const float p0 = fexp2(sv[nt][0] - mnew);
    const float p1 = fexp2(sv[nt][1] - mnew);
    const float p2 = fexp2(sv[nt][2] - mnew);
    const float p3 = fexp2(sv[nt][3] - mnew);
    rs += (p0 + p1) + (p2 + p3);
    bf16x4 w;
    w[0] = (bf16_t)p0; w[1] = (bf16_t)p1; w[2] = (bf16_t)p2; w[3] = (bf16_t)p3;
    *(bf16x4*)(plp + mr * 72 + nt * 16 + quad * 4) = w;
  }
  if (__all(mx <= mstv)) {
    lstv += rs;                        // alpha == 1 exactly, skip rescale
  } else {
    const float alpha = fexp2(mstv - mnew);
    mstv = mnew;
    lstv = alpha * lstv + rs;
#pragma unroll
    for (int nt = 0; nt < 4; ++nt)
#pragma unroll
      for (int r = 0; r < 4; ++r) ov[nt][r] *= alpha;
  }
}

// ---------------------------------------------------------------------------
// Kernel 2: causal flash attention, S^T formulation.  256 blocks x 1024 thr
// (16 waves).  Block owns paired 32-row groups (gA=pr, gB=127-pr) of batch
// b = bid&3 (XCD-pinned K/V).  Waves partitioned between groups by KV work;
// each wave owns 32 q-rows (2 subtiles sharing all K/V loads).
//   S^T = mfma(K, Q):  col(lane&15)=q, row(quad*4+reg)=kv  -> softmax row
//   reductions are in-lane + 2 shfl_xor, P^T is kv-consecutive in regs.
//   O^T = mfma(V, P^T): col(lane&15)=q, row(quad*4+reg)=h within tile nt.
// ---------------------------------------------------------------------------
__global__ __launch_bounds__(1024, 4) void attn_kernel(
    const bf16_t* __restrict__ qg, const bf16_t* __restrict__ kfr,
    const bf16_t* __restrict__ vfr, float* __restrict__ out)
{
  __shared__ __align__(16) char smem[73728];            // plds U cmbo
  __shared__ float cml[16][16][2];
  bf16_t* plds = (bf16_t*)smem;                         // 16 x 2304 elems
  float (*cmbo)[16][68] = (float (*)[16][68])smem;      // [16][16][68]

  const int tid  = threadIdx.x;
  const int lane = tid & 63;
  const int wave = tid >> 6;     // 0..15
  const int mr   = lane & 15;
  const int quad = lane >> 4;

  const int bid = blockIdx.x;    // 0..255
  const int b   = bid & 3;
  const int pr  = bid >> 2;      // 0..63
  const int gA  = pr;
  const int gB  = 127 - pr;
  const int nAw = (gA >> 1) + 1;
  const int nBw = (gB >> 1) + 1;
  int na = (16 * nAw + ((nAw + nBw) >> 1)) / (nAw + nBw);
  na = na < 1 ? 1 : (na > 15 ? 15 : na);

  const bool inA   = wave < na;
  const int g      = inA ? gA : gB;
  const int slot   = inA ? wave : wave - na;
  const int nsplit = inA ? na : 16 - na;
  const int q0     = g * 32;
  const int ktmax  = g >> 1;

  const size_t baseq = (size_t)b * TT * HSZ;
  const bf16_t* kb = kfr + (size_t)b * 64 * 4096;   // 64 tiles x 4096 elems
  const bf16_t* vb = vfr + (size_t)b * 64 * 4096;

  bf16_t* pl0 = plds + wave * 2304;
  bf16_t* pl1 = pl0 + 1152;

  // Q fragments (used as MFMA B operand): lane&15 = q-row, elems = h
  bf16x8 qf[2][2];
#pragma unroll
  for (int s = 0; s < 2; ++s) {
    const bf16_t* qp = qg + baseq + (size_t)(q0 + s * 16 + mr) * HSZ + quad * 8;
    qf[s][0] = *(const bf16x8*)qp;
    qf[s][1] = *(const bf16x8*)(qp + 32);
  }

  floatx4 o0[4], o1[4];            // O^T: lane q=mr, h = nt*16+quad*4+r
#pragma unroll
  for (int i = 0; i < 4; ++i) {
    o0[i] = (floatx4){0.f, 0.f, 0.f, 0.f};
    o1[i] = (floatx4){0.f, 0.f, 0.f, 0.f};
  }
  float mst[2] = {NEG_BIG, NEG_BIG};   // per-lane row stats (row = mr)
  float lst[2] = {0.f, 0.f};           // per-lane PARTIAL row sum (16 kv)

  for (int kt = slot; kt <= ktmax; kt += nsplit) {
    const int k0 = kt * 64;

    // ---- S^T for both subtiles: mfma(K, Q).  K fragments = A operand ----
    floatx4 s0[4], s1[4];
#pragma unroll
    for (int i = 0; i < 4; ++i) {
      s0[i] = (floatx4){0.f, 0.f, 0.f, 0.f};
      s1[i] = (floatx4){0.f, 0.f, 0.f, 0.f};
    }
#pragma unroll
    for (int nt = 0; nt < 4; ++nt) {
      const bf16_t* kp = kb + ((size_t)kt * 4 + nt) * 1024 + lane * 8;
      bf16x8 kb0 = *(const bf16x8*)kp;          // h 0..31
      bf16x8 kb1 = *(const bf16x8*)(kp + 512);  // h 32..63
      s0[nt] = __builtin_amdgcn_mfma_f32_16x16x32_bf16(kb0, qf[0][0], s0[nt], 0, 0, 0);
      s0[nt] = __builtin_amdgcn_mfma_f32_16x16x32_bf16(kb1, qf[0][1], s0[nt], 0, 0, 0);
      s1[nt] = __builtin_amdgcn_mfma_f32_16x16x32_bf16(kb0, qf[1][0], s1[nt], 0, 0, 0);
      s1[nt] = __builtin_amdgcn_mfma_f32_16x16x32_bf16(kb1, qf[1][1], s1[nt], 0, 0, 0);
    }

    // ---- causal mask (last tile only): kv = k0+nt*16+quad*4+r, q = q0+mr ----
    if (kt == ktmax) {
      const int qa0 = q0 + mr;
#pragma unroll
      for (int nt = 0; nt < 4; ++nt) {
#pragma unroll
        for (int r = 0; r < 4; ++r) {
          const int kv = k0 + nt * 16 + quad * 4 + r;
          if (kv > qa0)      s0[nt][r] = NEG_BIG;
          if (kv > qa0 + 16) s1[nt][r] = NEG_BIG;
        }
      }
    }

    // ---- softmax subtile 0 -> P0^T (packed b64 stores) ----
    softmax_step(s0, mst[0], lst[0], o0, pl0, mr, quad);

    // ---- V fragment loads kc=0 (kv 0..31), contiguous 1 KB each ----
    bf16x8 vfa[4];
#pragma unroll
    for (int nt = 0; nt < 4; ++nt)
      vfa[nt] = *(const bf16x8*)(vb + ((size_t)kt * 8 + nt) * 512 + lane * 8);

    // ---- softmax subtile 1 -> P1^T ----
    softmax_step(s1, mst[1], lst[1], o1, pl1, mr, quad);

    bf16x8 vfb[4];                 // kc=1 (kv 32..63)
#pragma unroll
    for (int nt = 0; nt < 4; ++nt)
      vfb[nt] = *(const bf16x8*)(vb + ((size_t)kt * 8 + nt) * 512 + 2048 + lane * 8);

    // ---- O^T += V * P^T ----
    {
      bf16x8 pa0 = *(bf16x8*)&pl0[mr * 72 + quad * 8];
      bf16x8 pa1 = *(bf16x8*)&pl1[mr * 72 + quad * 8];
#pragma unroll
      for (int nt = 0; nt < 4; ++nt) {
        o0[nt] = __builtin_amdgcn_mfma_f32_16x16x32_bf16(vfa[nt], pa0, o0[nt], 0, 0, 0);
        o1[nt] = __builtin_amdgcn_mfma_f32_16x16x32_bf16(vfa[nt], pa1, o1[nt], 0, 0, 0);
      }
      bf16x8 pb0 = *(bf16x8*)&pl0[mr * 72 + 32 + quad * 8];
      bf16x8 pb1 = *(bf16x8*)&pl1[mr * 72 + 32 + quad * 8];
#pragma unroll
      for (int nt = 0; nt < 4; ++nt) {
        o0[nt] = __builtin_amdgcn_mfma_f32_16x16x32_bf16(vfb[nt], pb0, o0[nt], 0, 0, 0);
        o1[nt] = __builtin_amdgcn_mfma_f32_16x16x32_bf16(vfb[nt], pb1, o1[nt], 0, 0, 0);
      }
    }
  }

  // ---- combine: per group over its wave-slots, one subtile per pass ----
  __syncthreads();   // all PV reads of plds done (cmbo overlays it)
#pragma unroll
  for (int s = 0; s < 2; ++s) {
    const float lsum = qsum(lst[s]);   // cross-quad: full row sum
    if (lane < 16) {
      cml[wave][lane][0] = mst[s];
      cml[wave][lane][1] = lsum;
    }
    __syncthreads();
    {
      const int lo = inA ? 0 : na;
      const int hi = inA ? na : 16;
      float mstar = cml[lo][mr][0];
      for (int i = lo + 1; i < hi; ++i) mstar = fmaxf(mstar, cml[i][mr][0]);
      const float scale = fexp2(mst[s] - mstar);
#pragma unroll
      for (int nt = 0; nt < 4; ++nt) {
        floatx4 t;
#pragma unroll
        for (int r = 0; r < 4; ++r) t[r] = (s ? o1[nt][r] : o0[nt][r]) * scale;
        *(floatx4*)&cmbo[wave][mr][nt * 16 + quad * 4] = t;   // row=q, col=h
      }
    }
    __syncthreads();
    {
      const int grp = tid >> 9;            // 0 = A, 1 = B
      const int row = (tid >> 5) & 15;
      const int c0  = (tid & 31) * 2;
      const int lo  = grp ? na : 0;
      const int hi  = grp ? 16 : na;
      const int gq0 = (grp ? gB : gA) * 32 + s * 16;
      float mstar = cml[lo][row][0];
      for (int i = lo + 1; i < hi; ++i) mstar = fmaxf(mstar, cml[i][row][0]);
      float l = 0.f;
      for (int i = lo; i < hi; ++i)
        l += cml[i][row][1] * fexp2(cml[i][row][0] - mstar);
      float sx = 0.f, sy = 0.f;
      for (int i = lo; i < hi; ++i) {
        float2 v = *(float2*)&cmbo[i][row][c0];
        sx += v.x; sy += v.y;
      }
      const float invl = 1.0f / l;
      float2 res; res.x = sx * invl; res.y = sy * invl;
      *(float2*)(out + baseq + (size_t)(gq0 + row) * HSZ + c0) = res;
    }
    __syncthreads();   // cml/cmbo reused by next pass
  }
}

// ---------------------------------------------------------------------------
extern "C" void kernel_launch(void* const* d_in, const int* in_sizes, int n_in,
                              void* d_out, int out_size, void* d_ws, size_t ws_size,
                              hipStream_t stream) {
  const float* x  = (const float*)d_in[0];
  const float* Wk = (const float*)d_in[1];
  const float* Wq = (const float*)d_in[2];
  const float* Wv = (const float*)d_in[3];
  float* out = (float*)d_out;

  bf16_t* ws  = (bf16_t*)d_ws;
  bf16_t* Wb  = ws + WB_OFF;
  bf16_t* qg  = ws + Q_OFF;
  bf16_t* kfr = ws + K_OFF;
  bf16_t* vfr = ws + V_OFF;

  wcvt_kernel<<<dim3(192), dim3(256), 0, stream>>>(Wk, Wq, Wv, Wb);
  qkv_proj_kernel<<<dim3(512), dim3(256), 0, stream>>>(x, Wb, qg, kfr, vfr);
  attn_kernel<<<dim3(256), dim3(1024), 0, stream>>>(qg, kfr, vfr, out);
}